// Round 3
// baseline (350.810 us; speedup 1.0000x reference)
//
#include <hip/hip_runtime.h>
#include <hip/hip_bf16.h>
#include <stdint.h>

#define N_VOX   (1 << 19)
#define CIN     64
#define COUT    128
#define TDIM    8
#define HDIM    512
#define WDIM    512
#define BIN_SHIFT 6
#define BINS    (1 << 17)          // (4*8*512*512) >> 6
#define EPSV    1e-5f

// d_out is FLOAT32 (reference output dtype): out_f [N,128] f32, then new_idx
// [N,4] as f32 values. Round 1/2 failure (absmax 257.359375 = ~252 + 5.3) was
// bf16 stores into the f32 buffer: new_idx bf16 writes at bf16-offset N*COUT
// landed at f32 element N*COUT/2 — inside output 0.
//
// ws layout (ints): hist[BINS] | cursor[BINS] | lin[N] | perm[N] | partials[128]
// total = 5,243,392 bytes.

// ---------------- sort pipeline ----------------

__global__ void k_hist(const int* __restrict__ idx, int* __restrict__ lin_arr,
                       int* __restrict__ hist) {
    int j = blockIdx.x * 256 + threadIdx.x;
    int4 v = *(const int4*)&idx[j * 4];
    int lin = ((v.x * TDIM + v.y) * HDIM + v.z) * WDIM + v.w;
    lin_arr[j] = lin;
    atomicAdd(&hist[lin >> BIN_SHIFT], 1);
}

// 128 blocks x 256 thr: each block sums 1024 bins -> partials[128]
__global__ void scan_partial(const int* __restrict__ hist, int* __restrict__ partials) {
    __shared__ int sdata[256];
    int base = blockIdx.x * 1024;
    int t = threadIdx.x;
    int s = hist[base + t] + hist[base + t + 256] + hist[base + t + 512] + hist[base + t + 768];
    sdata[t] = s;
    __syncthreads();
    for (int off = 128; off > 0; off >>= 1) {
        if (t < off) sdata[t] += sdata[t + off];
        __syncthreads();
    }
    if (t == 0) partials[blockIdx.x] = sdata[0];
}

// 1 block x 128 thr: exclusive scan of partials[128]
__global__ void scan_top(int* __restrict__ partials) {
    __shared__ int sdata[128];
    int t = threadIdx.x;
    sdata[t] = partials[t];
    __syncthreads();
    for (int off = 1; off < 128; off <<= 1) {
        int v = 0;
        if (t >= off) v = sdata[t - off];
        __syncthreads();
        sdata[t] += v;
        __syncthreads();
    }
    partials[t] = t ? sdata[t - 1] : 0;   // exclusive
}

// 128 blocks x 256 thr: per-block scan of 1024 bins (4/thread) + block prefix
__global__ void scan_final(const int* __restrict__ hist, const int* __restrict__ partials,
                           int* __restrict__ cursor) {
    __shared__ int sscan[256];
    int t = threadIdx.x;
    int base = blockIdx.x * 1024 + t * 4;
    int4 v = *(const int4*)&hist[base];
    int s0 = v.x, s1 = v.x + v.y, s2 = s1 + v.z, s3 = s2 + v.w;
    sscan[t] = s3;
    __syncthreads();
    for (int off = 1; off < 256; off <<= 1) {
        int u = 0;
        if (t >= off) u = sscan[t - off];
        __syncthreads();
        sscan[t] += u;
        __syncthreads();
    }
    int prefix = partials[blockIdx.x] + (t ? sscan[t - 1] : 0);
    int4 e;
    e.x = prefix;
    e.y = prefix + s0;
    e.z = prefix + s1;
    e.w = prefix + s2;
    *(int4*)&cursor[base] = e;
}

__global__ void k_scatter(const int* __restrict__ lin_arr, int* __restrict__ cursor,
                          int* __restrict__ perm) {
    int j = blockIdx.x * 256 + threadIdx.x;
    int lin = lin_arr[j];
    int slot = atomicAdd(&cursor[lin >> BIN_SHIFT], 1);
    perm[slot] = j;
}

// after scatter, cursor[b] = start + count; start = cursor[b] - hist[b]
__global__ void k_fixup(const int* __restrict__ hist, const int* __restrict__ cursor,
                        const int* __restrict__ lin_arr, int* __restrict__ perm) {
    int b = blockIdx.x * 256 + threadIdx.x;
    int c = hist[b];
    if (c < 2) return;
    int s = cursor[b] - c;
    for (int i = 1; i < c; i++) {
        int pj = perm[s + i];
        unsigned long long kj =
            ((unsigned long long)(unsigned)lin_arr[pj] << 19) | (unsigned)pj;
        int m = i - 1;
        while (m >= 0) {
            int pm = perm[s + m];
            unsigned long long km =
                ((unsigned long long)(unsigned)lin_arr[pm] << 19) | (unsigned)pm;
            if (km <= kj) break;
            perm[s + m + 1] = pm;
            m--;
        }
        perm[s + m + 1] = pj;
    }
}

// ---------------- main fused GEMM + LN + mask ----------------

__global__ __launch_bounds__(256) void k_main(
    const float* __restrict__ feats, const int* __restrict__ idx,
    const float* __restrict__ weight, const float* __restrict__ gamma,
    const float* __restrict__ beta, const int* __restrict__ perm,
    float* __restrict__ out) {
    __shared__ float Wlds[CIN][COUT];       // 32 KB
    __shared__ float featb[4][4][CIN];      // 4 KB, per-wave rows
    int tid = threadIdx.x;

    // stage W: 8192 floats = 2048 float4, 256 threads x 8
    #pragma unroll
    for (int i = 0; i < 8; i++) {
        int e = tid + i * 256;
        *(float4*)&((float*)Wlds)[e * 4] = *(const float4*)&weight[e * 4];
    }

    int w = tid >> 6, lane = tid & 63;
    int rbase = blockIdx.x * 16 + w * 4;

    int jrow[4];
    #pragma unroll
    for (int i = 0; i < 4; i++) {
        int r = rbase + i;
        int j = perm[r];
        jrow[i] = j;
        featb[w][i][lane] = feats[(size_t)j * CIN + lane];
    }
    __syncthreads();   // covers Wlds staging AND cross-lane featb visibility

    float2 acc[4];
    #pragma unroll
    for (int i = 0; i < 4; i++) { acc[i].x = 0.f; acc[i].y = 0.f; }

    #pragma unroll 4
    for (int k0 = 0; k0 < CIN; k0 += 4) {
        float4 f[4];
        #pragma unroll
        for (int i = 0; i < 4; i++) f[i] = *(float4*)&featb[w][i][k0];
        #pragma unroll
        for (int kk = 0; kk < 4; kk++) {
            float2 wv = *(float2*)&Wlds[k0 + kk][lane * 2];
            #pragma unroll
            for (int i = 0; i < 4; i++) {
                float fk = ((const float*)&f[i])[kk];
                acc[i].x += fk * wv.x;
                acc[i].y += fk * wv.y;
            }
        }
    }

    float2 gv = *(const float2*)&gamma[lane * 2];
    float2 bv = *(const float2*)&beta[lane * 2];

    #pragma unroll
    for (int i = 0; i < 4; i++) {
        int r = rbase + i;
        float v0 = acc[i].x, v1 = acc[i].y;
        float s = v0 + v1;
        float sq = v0 * v0 + v1 * v1;
        #pragma unroll
        for (int off = 32; off > 0; off >>= 1) {
            s  += __shfl_xor(s, off);
            sq += __shfl_xor(sq, off);
        }
        float mean = s * (1.0f / COUT);
        float var  = fmaxf(sq * (1.0f / COUT) - mean * mean, 0.0f);
        float rstd = rsqrtf(var + EPSV);

        int4 iv = *(const int4*)&idx[jrow[i] * 4];
        bool mask = ((iv.z & 1) == 0) && ((iv.w & 1) == 0);

        float2 o;
        o.x = mask ? ((v0 - mean) * rstd * gv.x + bv.x) : 0.0f;
        o.y = mask ? ((v1 - mean) * rstd * gv.y + bv.y) : 0.0f;
        *(float2*)&out[(size_t)r * COUT + lane * 2] = o;   // f32 store, coalesced

        if (lane < 4) {
            int comp = (lane == 0) ? iv.x
                     : (lane == 1) ? iv.y
                     : (lane == 2) ? (iv.z >> 1)
                                   : (iv.w >> 1);
            if (!mask) comp = -1;
            out[(size_t)N_VOX * COUT + (size_t)r * 4 + lane] = (float)comp;
        }
    }
}

extern "C" void kernel_launch(void* const* d_in, const int* in_sizes, int n_in,
                              void* d_out, int out_size, void* d_ws, size_t ws_size,
                              hipStream_t stream) {
    const float* feats  = (const float*)d_in[0];
    const int*   idx    = (const int*)d_in[1];
    const float* weight = (const float*)d_in[2];
    const float* gamma  = (const float*)d_in[3];
    const float* beta   = (const float*)d_in[4];
    float* out = (float*)d_out;

    int* ws       = (int*)d_ws;
    int* hist     = ws;                        // BINS
    int* cursor   = ws + BINS;                 // BINS
    int* lin_arr  = ws + 2 * BINS;             // N
    int* perm     = ws + 2 * BINS + N_VOX;     // N
    int* partials = ws + 2 * BINS + 2 * N_VOX; // 128

    hipMemsetAsync(hist, 0, BINS * sizeof(int), stream);
    k_hist<<<N_VOX / 256, 256, 0, stream>>>(idx, lin_arr, hist);
    scan_partial<<<BINS / 1024, 256, 0, stream>>>(hist, partials);
    scan_top<<<1, 128, 0, stream>>>(partials);
    scan_final<<<BINS / 1024, 256, 0, stream>>>(hist, partials, cursor);
    k_scatter<<<N_VOX / 256, 256, 0, stream>>>(lin_arr, cursor, perm);
    k_fixup<<<BINS / 256, 256, 0, stream>>>(hist, cursor, lin_arr, perm);
    k_main<<<N_VOX / 16, 256, 0, stream>>>(feats, idx, weight, gamma, beta, perm, out);
}